// Round 3
// baseline (26296.420 us; speedup 1.0000x reference)
//
#include <hip/hip_runtime.h>

#define B_ 64
#define T_ 2048
#define I_ 256
#define H_ 512
#define O_ 256
#define GBC 2            // batch groups
#define GHC 32           // hidden-slice groups
#define MB (B_/GBC)      // 32 rows per WG
#define HS (H_/GHC)      // 16 hidden units per WG
#define NC (4*HS)        // 64 gate cols per WG
#define KK (I_+H_)       // 768 fused K (x | h)
#define KSTEPS (KK/32)   // 24 MFMA K-steps
#define GSTR 68          // gates LDS row stride (pad)

// LDS layout (bytes)
#define XSTR 528         // 256 bf16 + 8 pad  (132 dw = 4 mod 32)
#define XBUFB (MB*XSTR)  // 16,896 per x buffer
#define HSTR 1040        // 512 bf16 + 8 pad  (260 dw = 4 mod 32)
#define HOFF (2*XBUFB)   // 33,792
#define GOFF (HOFF + MB*HSTR)  // 67,072
#define LDSB (GOFF + MB*GSTR*4) // 75,776

typedef __attribute__((ext_vector_type(8))) short short8;
typedef __attribute__((ext_vector_type(4))) float f32x4;
typedef __attribute__((ext_vector_type(4))) float float4v;

__device__ __forceinline__ unsigned short f2bf(float f) {
  union { float f; unsigned u; } v; v.f = f;
  unsigned r = v.u + 0x7fffu + ((v.u >> 16) & 1u);   // RNE
  return (unsigned short)(r >> 16);
}
__device__ __forceinline__ unsigned asu(float f) { union { float f; unsigned u; } v; v.f = f; return v.u; }
__device__ __forceinline__ float asf(unsigned u) { union { unsigned u; float f; } v; v.u = u; return v.f; }

// ---------------- init: zero hexf[2][B_][H_] ----------------
__global__ void init_kernel(unsigned int* __restrict__ p, int n4) {
  int i = blockIdx.x * 256 + threadIdx.x;
  if (i < n4) p[i] = 0u;
}

// ---------------- weight/bias repack: Wcat[gh][c][k] bf16 ----------------
__global__ void prep_kernel(const float* __restrict__ Wx, const float* __restrict__ Wh,
                            const float* __restrict__ bias,
                            unsigned short* __restrict__ Wcat, float* __restrict__ bcat) {
  int idx = blockIdx.x * 256 + threadIdx.x;      // over [KK][2048], exact
  int k = idx >> 11;
  int gcol = idx & 2047;
  float v = (k < I_) ? Wx[k * 2048 + gcol] : Wh[(k - I_) * 2048 + gcol];
  int gate = gcol >> 9, j = gcol & 511;
  int gh = j >> 4, jj = j & 15;
  int c = (gate << 4) | jj;                      // local col = gate*16+jj
  Wcat[((size_t)(gh * NC + c) * KK) + k] = f2bf(v);
  if (k == 0) bcat[gh * NC + c] = bias[gcol];
}

// ---------------- persistent LSTM recurrence ----------------
__global__ __launch_bounds__(512, 1) void lstm_kernel(
    const float* __restrict__ x,
    const unsigned short* __restrict__ Wcat,
    const float* __restrict__ bcat,
    unsigned* hexf,                      // [2][B_][H_] tagged f32 (LLC traffic)
    float* __restrict__ hout, float* __restrict__ cout)
{
  __shared__ __align__(16) char L[LDSB];
  float* gates = reinterpret_cast<float*>(&L[GOFF]);

  const int tid = threadIdx.x;
  const int wg = blockIdx.x;
  const int gb = wg >> 5, gh = wg & 31;
  const int bbase = gb * MB;
  const int hbase = gh * HS;
  const int lane = tid & 63, wid = tid >> 6;
  const int mt = wid >> 2, nt = wid & 3;           // 2 M-tiles x 4 N-tiles = 8 waves

  // --- W fragments: resident in VGPRs (24 x 4 VGPR = 96); pinned via opaque asm defs
  short8 wfrag[KSTEPS];
  {
    const int col = nt * 16 + (lane & 15);
    const short8* wsrc = reinterpret_cast<const short8*>(
        Wcat + (size_t)(gh * NC + col) * KK + ((lane >> 4) * 8));
#pragma unroll
    for (int kk = 0; kk < KSTEPS; ++kk) wfrag[kk] = wsrc[kk * 4];
#pragma unroll
    for (int kk = 0; kk < KSTEPS; ++kk) asm volatile("" : "+v"(wfrag[kk]));
  }
  const float bias_l = bcat[gh * NC + nt * 16 + (lane & 15)];

  // staging geometry (identical for x and h): wave w owns rows 4w..4w+3
  const int srow = 4 * wid + (lane >> 4);
  const int xc0 = (lane & 15) * 16;                // 16 f32 per lane (x)
  const int hc0 = (lane & 15) * 32;                // 32 f32 per lane (h)
  const int crow = tid >> 4, cjj = tid & 15;       // combine mapping (1 cell/thread)
  const int arow = mt * 16 + (lane & 15);          // GEMM A row
  const int afr = (lane >> 4) * 16;                // GEMM A frag byte offset

  float creg = 0.f;

  // ---- prologue: stage x_0 into Xbuf[1]
  {
    const float* xp = x + ((size_t)(bbase + srow) * T_ + 0) * I_ + xc0;
    char* xd = &L[XBUFB + srow * XSTR + xc0 * 2];
#pragma unroll
    for (int c2 = 0; c2 < 2; ++c2) {
      float4v a = *reinterpret_cast<const float4v*>(xp + 8 * c2);
      float4v b4 = *reinterpret_cast<const float4v*>(xp + 8 * c2 + 4);
      short8 o;
      o[0] = (short)f2bf(a[0]);  o[1] = (short)f2bf(a[1]);
      o[2] = (short)f2bf(a[2]);  o[3] = (short)f2bf(a[3]);
      o[4] = (short)f2bf(b4[0]); o[5] = (short)f2bf(b4[1]);
      o[6] = (short)f2bf(b4[2]); o[7] = (short)f2bf(b4[3]);
      *reinterpret_cast<short8*>(xd + 16 * c2) = o;
    }
  }

  for (int s = 1; s <= T_; ++s) {
    const int bprev = (s - 1) & 1, bcur = s & 1;
    const unsigned tagexp = (unsigned)((s - 1) & 3);

    // ---- P1a: issue next-step x loads (fly during the h poll)
    float4v xr[4];
    if (s < T_) {
      const float* xp = x + ((size_t)(bbase + srow) * T_ + s) * I_ + xc0;
#pragma unroll
      for (int i = 0; i < 4; ++i) xr[i] = *reinterpret_cast<const float4v*>(xp + 4 * i);
    }

    // ---- P1b: self-validating h poll (tag = 2 LSBs of f32 mantissa = (s-1)&3)
    unsigned hv[32];
    {
      unsigned* hsrc = hexf + (size_t)bprev * B_ * H_ + (size_t)(bbase + srow) * H_ + hc0;
      int bud = 1 << 18;
      while (true) {
#pragma unroll
        for (int i = 0; i < 32; ++i)
          hv[i] = __hip_atomic_load(hsrc + i, __ATOMIC_RELAXED, __HIP_MEMORY_SCOPE_AGENT);
        unsigned ok = 1u;
#pragma unroll
        for (int i = 0; i < 32; ++i) ok &= (unsigned)((hv[i] & 3u) == tagexp);
        if (__all((int)ok) || --bud < 0) break;
      }
    }

    // ---- P1c: stage h to LDS (bf16)
    {
      char* hd = &L[HOFF + srow * HSTR + hc0 * 2];
#pragma unroll
      for (int c8 = 0; c8 < 4; ++c8) {
        short8 o;
#pragma unroll
        for (int j = 0; j < 8; ++j) o[j] = (short)f2bf(asf(hv[c8 * 8 + j]));
        *reinterpret_cast<short8*>(hd + 16 * c8) = o;
      }
    }

    // ---- P1d: stage next-step x to LDS (bf16), buffer (s+1)&1
    if (s < T_) {
      char* xd = &L[((s + 1) & 1) * XBUFB + srow * XSTR + xc0 * 2];
#pragma unroll
      for (int c2 = 0; c2 < 2; ++c2) {
        float4v a = xr[2 * c2], b4 = xr[2 * c2 + 1];
        short8 o;
        o[0] = (short)f2bf(a[0]);  o[1] = (short)f2bf(a[1]);
        o[2] = (short)f2bf(a[2]);  o[3] = (short)f2bf(a[3]);
        o[4] = (short)f2bf(b4[0]); o[5] = (short)f2bf(b4[1]);
        o[6] = (short)f2bf(b4[2]); o[7] = (short)f2bf(b4[3]);
        *reinterpret_cast<short8*>(xd + 16 * c2) = o;
      }
    }
    __syncthreads();   // B1

    // ---- P2: GEMM  gates = [x_t | h] x Wfrag + bias
    {
      f32x4 acc = {bias_l, bias_l, bias_l, bias_l};
      const char* xb = &L[(s & 1) * XBUFB + arow * XSTR + afr];
#pragma unroll
      for (int kk = 0; kk < 8; ++kk) {
        short8 a = *reinterpret_cast<const short8*>(xb + kk * 64);
        acc = __builtin_amdgcn_mfma_f32_16x16x32_bf16(a, wfrag[kk], acc, 0, 0, 0);
      }
      const char* hb = &L[HOFF + arow * HSTR + afr];
#pragma unroll
      for (int kk = 0; kk < 16; ++kk) {
        short8 a = *reinterpret_cast<const short8*>(hb + kk * 64);
        acc = __builtin_amdgcn_mfma_f32_16x16x32_bf16(a, wfrag[8 + kk], acc, 0, 0, 0);
      }
      const int col = nt * 16 + (lane & 15);
      const int r0 = mt * 16 + ((lane >> 4) << 2);
      gates[(r0 + 0) * GSTR + col] = acc[0];
      gates[(r0 + 1) * GSTR + col] = acc[1];
      gates[(r0 + 2) * GSTR + col] = acc[2];
      gates[(r0 + 3) * GSTR + col] = acc[3];
    }
    __syncthreads();   // B2

    // ---- P3: nonlinearities + cell update + tagged h publish (relaxed agent store)
    {
      const float* grow = &gates[crow * GSTR];
      float ig = grow[cjj], fg = grow[16 + cjj], gg = grow[32 + cjj], og = grow[48 + cjj];
      float i_ = 1.f / (1.f + __expf(-ig));
      float f_ = 1.f / (1.f + __expf(-fg));
      float g_ = 1.f - 2.f / (__expf(2.f * gg) + 1.f);   // tanh
      float o_ = 1.f / (1.f + __expf(-og));
      creg = f_ * creg + i_ * g_;
      float hvf = o_ * (1.f - 2.f / (__expf(2.f * creg) + 1.f));
      unsigned tagged = (asu(hvf) & ~3u) | (unsigned)(s & 3);
      __hip_atomic_store(
          hexf + (size_t)bcur * B_ * H_ + (size_t)(bbase + crow) * H_ + hbase + cjj,
          tagged, __ATOMIC_RELAXED, __HIP_MEMORY_SCOPE_AGENT);
      if (s == T_) {
        hout[(bbase + crow) * H_ + hbase + cjj] = hvf;
        cout[(bbase + crow) * H_ + hbase + cjj] = creg;
      }
    }
    // no barrier needed: next P1 touches only Hlds/Xlds (safe past B2) and global
  }
}

// ---------------- final FC: y = h_T @ fc_w^T + fc_b ----------------
__global__ void fc_kernel(const float* __restrict__ hT, const float* __restrict__ fcw,
                          const float* __restrict__ fcb, float* __restrict__ y) {
  __shared__ float hr[H_];
  const int b = blockIdx.x, o = threadIdx.x;
  hr[o] = hT[b * H_ + o];
  hr[o + 256] = hT[b * H_ + 256 + o];
  __syncthreads();
  const float4v* w = reinterpret_cast<const float4v*>(fcw + (size_t)o * H_);
  const float4v* h4 = reinterpret_cast<const float4v*>(hr);
  float s0 = 0.f, s1 = 0.f, s2 = 0.f, s3 = 0.f;
#pragma unroll 8
  for (int k = 0; k < H_ / 4; ++k) {
    float4v wv = w[k], hv = h4[k];
    s0 += wv[0] * hv[0]; s1 += wv[1] * hv[1];
    s2 += wv[2] * hv[2]; s3 += wv[3] * hv[3];
  }
  y[b * O_ + o] = s0 + s1 + s2 + s3 + fcb[o];
}

extern "C" void kernel_launch(void* const* d_in, const int* in_sizes, int n_in,
                              void* d_out, int out_size, void* d_ws, size_t ws_size,
                              hipStream_t stream) {
  const float* x    = (const float*)d_in[0];
  const float* Wx   = (const float*)d_in[1];
  const float* Wh   = (const float*)d_in[2];
  const float* bias = (const float*)d_in[3];
  const float* fcw  = (const float*)d_in[4];
  const float* fcb  = (const float*)d_in[5];
  float* out = (float*)d_out;                 // [y 16384 | h 32768 | c 32768]

  char* ws = (char*)d_ws;
  unsigned short* Wcat = (unsigned short*)ws;                       // 3,145,728 B
  float* bcat          = (float*)(ws + 3145728);                    //     8,192 B
  unsigned* hexf       = (unsigned*)(ws + 3145728 + 8192);          //   262,144 B

  // zero hexf (both buffers; tag 0 == valid h_0) — every call (buffers persist!)
  init_kernel<<<dim3(256), dim3(256), 0, stream>>>((unsigned int*)hexf, 65536);
  // repack weights to bf16 [32][64][768] + bias [32][64]
  prep_kernel<<<dim3((KK * 2048) / 256), dim3(256), 0, stream>>>(Wx, Wh, bias, Wcat, bcat);
  // persistent recurrence: 64 WGs (2 batch groups x 32 hidden slices), 512 threads
  lstm_kernel<<<dim3(GBC * GHC), dim3(512), 0, stream>>>(
      x, Wcat, bcat, hexf, out + 16384, out + 16384 + 32768);
  // final projection
  fc_kernel<<<dim3(B_), dim3(256), 0, stream>>>(out + 16384, fcw, fcb, out);
}

// Round 4
// 6240.358 us; speedup vs baseline: 4.2139x; 4.2139x over previous
//
#include <hip/hip_runtime.h>

#define B_ 64
#define T_ 2048
#define I_ 256
#define H_ 512
#define O_ 256
#define GBC 2            // batch groups
#define GHC 32           // hidden-slice groups
#define MB (B_/GBC)      // 32 rows per WG
#define HS (H_/GHC)      // 16 hidden units per WG
#define NC (4*HS)        // 64 gate cols per WG
#define KK (I_+H_)       // 768 fused K (x | h)
#define GSTR 68          // gates LDS row stride (dwords, pad)

// LDS layout (bytes)
#define XSTR 528         // 512 B bf16 row + 16 pad  (132 dw = 4 mod 32)
#define XBUFB (MB*XSTR)  // 16,896 per x buffer
#define HSTR 1040        // 1024 B bf16 row + 16 pad (260 dw = 4 mod 32)
#define HOFF (2*XBUFB)   // 33,792
#define GOFF (HOFF + MB*HSTR)   // 67,072
#define LDSB (GOFF + MB*GSTR*4) // 75,776

typedef __attribute__((ext_vector_type(8))) short short8;
typedef __attribute__((ext_vector_type(4))) float f32x4;
typedef __attribute__((ext_vector_type(4))) float float4v;
typedef __attribute__((ext_vector_type(4))) int int4v;

__device__ __forceinline__ unsigned short f2bf(float f) {
  union { float f; unsigned u; } v; v.f = f;
  unsigned r = v.u + 0x7fffu + ((v.u >> 16) & 1u);   // RNE
  return (unsigned short)(r >> 16);
}
__device__ __forceinline__ unsigned asu(float f) { union { float f; unsigned u; } v; v.f = f; return v.u; }
__device__ __forceinline__ float asf(unsigned u) { union { unsigned u; float f; } v; v.u = u; return v.f; }

__device__ __forceinline__ short8 pack8(float4v a, float4v b) {
  short8 o;
  o[0] = (short)f2bf(a[0]); o[1] = (short)f2bf(a[1]);
  o[2] = (short)f2bf(a[2]); o[3] = (short)f2bf(a[3]);
  o[4] = (short)f2bf(b[0]); o[5] = (short)f2bf(b[1]);
  o[6] = (short)f2bf(b[2]); o[7] = (short)f2bf(b[3]);
  return o;
}

// agent-coherent 16-B load (bypasses stale local L2; LLC-served)
__device__ __forceinline__ void ld_x4_sc1(int4v& v, const unsigned* p) {
  asm volatile("global_load_dwordx4 %0, %1, off sc1" : "=v"(v) : "v"(p) : "memory");
}

// ---------------- init: zero hexf[2][B_][H_] ----------------
__global__ void init_kernel(unsigned int* __restrict__ p, int n4) {
  int i = blockIdx.x * 256 + threadIdx.x;
  if (i < n4) p[i] = 0u;
}

// ---------------- weight/bias repack: Wcat[gh][c][k] bf16 ----------------
__global__ void prep_kernel(const float* __restrict__ Wx, const float* __restrict__ Wh,
                            const float* __restrict__ bias,
                            unsigned short* __restrict__ Wcat, float* __restrict__ bcat) {
  int idx = blockIdx.x * 256 + threadIdx.x;      // over [KK][2048], exact
  int k = idx >> 11;
  int gcol = idx & 2047;
  float v = (k < I_) ? Wx[k * 2048 + gcol] : Wh[(k - I_) * 2048 + gcol];
  int gate = gcol >> 9, j = gcol & 511;
  int gh = j >> 4, jj = j & 15;
  int c = (gate << 4) | jj;                      // local col = gate*16+jj
  Wcat[((size_t)(gh * NC + c) * KK) + k] = f2bf(v);
  if (k == 0) bcat[gh * NC + c] = bias[gcol];
}

// ---------------- persistent LSTM recurrence ----------------
__global__ __launch_bounds__(512, 1) void lstm_kernel(
    const float* __restrict__ x,
    const unsigned short* __restrict__ Wcat,
    const float* __restrict__ bcat,
    unsigned* hexf,                      // [2][B_][H_] tagged f32 (LLC traffic)
    float* __restrict__ hout, float* __restrict__ cout)
{
  __shared__ __align__(16) char L[LDSB];
  float* gates = reinterpret_cast<float*>(&L[GOFF]);

  const int tid = threadIdx.x;
  const int wg = blockIdx.x;
  // XCD-aware: wg%8 in {0..3} -> batch group 0, {4..7} -> group 1
  const int gb = (wg >> 2) & 1;
  const int gh = ((wg >> 3) << 2) | (wg & 3);
  const int bbase = gb * MB;
  const int hbase = gh * HS;
  const int lane = tid & 63, wid = tid >> 6;
  const int mt = wid >> 2, nt = wid & 3;           // 2 M-tiles x 4 N-tiles = 8 waves

  // --- W fragments: pinned into AGPRs (24 x 4 regs = 96; MFMA reads B from AGPR)
  short8 wfrag[24];
  {
    const int col = nt * 16 + (lane & 15);
    const short8* wsrc = reinterpret_cast<const short8*>(
        Wcat + (size_t)(gh * NC + col) * KK + ((lane >> 4) * 8));
#pragma unroll
    for (int kk = 0; kk < 24; ++kk) wfrag[kk] = wsrc[kk * 4];
#pragma unroll
    for (int kk = 0; kk < 24; ++kk) asm volatile("" : "+a"(wfrag[kk]));
  }
  const float bias_l = bcat[gh * NC + nt * 16 + (lane & 15)];

  const int l31 = lane & 31, lhi = lane >> 5;
  const int crow = tid >> 4, cjj = tid & 15;       // nonlin mapping (1 cell/thread)
  const int arow = mt * 16 + (lane & 15);          // GEMM A row
  const int afr = (lane >> 4) * 16;                // GEMM A frag byte offset

  float creg = 0.f;
  float4v xr[4];
  int bud = 1 << 20;

  // ---- prologue: stage x[0] -> xbuf[1]; preload xr = x[1]
#pragma unroll
  for (int p = 0; p < 2; ++p) {
    const int xrow = 4 * wid + 2 * p + lhi;
    const float* xp = x + ((size_t)(bbase + xrow) * T_ + 0) * I_ + 8 * l31;
    float4v a = *reinterpret_cast<const float4v*>(xp);
    float4v b = *reinterpret_cast<const float4v*>(xp + 4);
    *reinterpret_cast<short8*>(&L[XBUFB + xrow * XSTR + 16 * l31]) = pack8(a, b);
  }
#pragma unroll
  for (int p = 0; p < 2; ++p) {
    const int xrow = 4 * wid + 2 * p + lhi;
    const float* xp = x + ((size_t)(bbase + xrow) * T_ + 1) * I_ + 8 * l31;
    xr[2 * p] = *reinterpret_cast<const float4v*>(xp);
    xr[2 * p + 1] = *reinterpret_cast<const float4v*>(xp + 4);
  }

  for (int s = 1; s <= T_; ++s) {
    const int bprev = (s - 1) & 1, bcur = s & 1;
    const unsigned tagexp = (unsigned)((s - 1) & 3);

    // ---- P0: stage xr (= x[s]) into xbuf[(s+1)&1]; issue loads of x[s+1]
    if (s < T_) {
#pragma unroll
      for (int p = 0; p < 2; ++p) {
        const int xrow = 4 * wid + 2 * p + lhi;
        *reinterpret_cast<short8*>(&L[((s + 1) & 1) * XBUFB + xrow * XSTR + 16 * l31]) =
            pack8(xr[2 * p], xr[2 * p + 1]);
      }
      if (s + 1 < T_) {
#pragma unroll
        for (int p = 0; p < 2; ++p) {
          const int xrow = 4 * wid + 2 * p + lhi;
          const float* xp = x + ((size_t)(bbase + xrow) * T_ + (s + 1)) * I_ + 8 * l31;
          xr[2 * p] = *reinterpret_cast<const float4v*>(xp);
          xr[2 * p + 1] = *reinterpret_cast<const float4v*>(xp + 4);
        }
      }
    }

    // ---- P1: x-part GEMM (K=0..255) on xbuf[s&1]
    f32x4 acc = {bias_l, bias_l, bias_l, bias_l};
    {
      const char* xb = &L[(s & 1) * XBUFB + arow * XSTR + afr];
#pragma unroll
      for (int kk = 0; kk < 8; ++kk) {
        short8 a = *reinterpret_cast<const short8*>(xb + kk * 64);
        acc = __builtin_amdgcn_mfma_f32_16x16x32_bf16(a, wfrag[kk], acc, 0, 0, 0);
      }
    }

    // ---- P2: coalesced self-validating h poll (wave w owns rows {8p+w}, lane -> 8 fp32)
    int4v hv[8];
    {
      const unsigned* hb = hexf + (size_t)bprev * B_ * H_ + (size_t)bbase * H_ + 8 * lane;
      while (true) {
#pragma unroll
        for (int p = 0; p < 4; ++p) {
          const unsigned* rp = hb + (size_t)(p * 8 + wid) * H_;
          ld_x4_sc1(hv[2 * p], rp);
          ld_x4_sc1(hv[2 * p + 1], rp + 4);
        }
        asm volatile("s_waitcnt vmcnt(0)" ::: "memory");
        __builtin_amdgcn_sched_barrier(0);
        int ok = 1;
#pragma unroll
        for (int i = 0; i < 8; ++i)
#pragma unroll
          for (int j = 0; j < 4; ++j)
            ok &= (int)(((unsigned)hv[i][j] & 3u) == tagexp);
        if (__all(ok) || --bud < 0) break;
      }
    }

    // ---- P3: stage h -> LDS bf16, lane-contiguous 16 B (conflict-free)
#pragma unroll
    for (int p = 0; p < 4; ++p) {
      float4v a, b;
#pragma unroll
      for (int j = 0; j < 4; ++j) { a[j] = asf((unsigned)hv[2 * p][j]); b[j] = asf((unsigned)hv[2 * p + 1][j]); }
      *reinterpret_cast<short8*>(&L[HOFF + (p * 8 + wid) * HSTR + 16 * lane]) = pack8(a, b);
    }
    __syncthreads();   // B1

    // ---- P4: h-part GEMM (K=256..767) + gates write
    {
      const char* hbq = &L[HOFF + arow * HSTR + afr];
#pragma unroll
      for (int kk = 0; kk < 16; ++kk) {
        short8 a = *reinterpret_cast<const short8*>(hbq + kk * 64);
        acc = __builtin_amdgcn_mfma_f32_16x16x32_bf16(a, wfrag[8 + kk], acc, 0, 0, 0);
      }
      const int col = nt * 16 + (lane & 15);
      const int r0 = mt * 16 + ((lane >> 4) << 2);
      gates[(r0 + 0) * GSTR + col] = acc[0];
      gates[(r0 + 1) * GSTR + col] = acc[1];
      gates[(r0 + 2) * GSTR + col] = acc[2];
      gates[(r0 + 3) * GSTR + col] = acc[3];
    }
    __syncthreads();   // B2

    // ---- P5: nonlinearities + cell update + tagged h publish
    {
      const float* grow = &gates[crow * GSTR];
      float ig = grow[cjj], fg = grow[16 + cjj], gg = grow[32 + cjj], og = grow[48 + cjj];
      float i_ = 1.f / (1.f + __expf(-ig));
      float f_ = 1.f / (1.f + __expf(-fg));
      float g_ = 1.f - 2.f / (__expf(2.f * gg) + 1.f);   // tanh
      float o_ = 1.f / (1.f + __expf(-og));
      creg = f_ * creg + i_ * g_;
      float hvf = o_ * (1.f - 2.f / (__expf(2.f * creg) + 1.f));
      unsigned tagged = (asu(hvf) & ~3u) | (unsigned)(s & 3);
      __hip_atomic_store(
          hexf + (size_t)bcur * B_ * H_ + (size_t)(bbase + crow) * H_ + hbase + cjj,
          tagged, __ATOMIC_RELAXED, __HIP_MEMORY_SCOPE_AGENT);
      if (s == T_) {
        hout[(bbase + crow) * H_ + hbase + cjj] = hvf;
        cout[(bbase + crow) * H_ + hbase + cjj] = creg;
      }
    }
    // no trailing barrier: next P0/P1 touch xbuf[(s+2)&1]/xbuf[(s+1)&1] & regs only
  }
}

// ---------------- final FC: y = h_T @ fc_w^T + fc_b ----------------
__global__ void fc_kernel(const float* __restrict__ hT, const float* __restrict__ fcw,
                          const float* __restrict__ fcb, float* __restrict__ y) {
  __shared__ float hr[H_];
  const int b = blockIdx.x, o = threadIdx.x;
  hr[o] = hT[b * H_ + o];
  hr[o + 256] = hT[b * H_ + 256 + o];
  __syncthreads();
  const float4v* w = reinterpret_cast<const float4v*>(fcw + (size_t)o * H_);
  const float4v* h4 = reinterpret_cast<const float4v*>(hr);
  float s0 = 0.f, s1 = 0.f, s2 = 0.f, s3 = 0.f;
#pragma unroll 8
  for (int k = 0; k < H_ / 4; ++k) {
    float4v wv = w[k], hv = h4[k];
    s0 += wv[0] * hv[0]; s1 += wv[1] * hv[1];
    s2 += wv[2] * hv[2]; s3 += wv[3] * hv[3];
  }
  y[b * O_ + o] = s0 + s1 + s2 + s3 + fcb[o];
}

extern "C" void kernel_launch(void* const* d_in, const int* in_sizes, int n_in,
                              void* d_out, int out_size, void* d_ws, size_t ws_size,
                              hipStream_t stream) {
  const float* x    = (const float*)d_in[0];
  const float* Wx   = (const float*)d_in[1];
  const float* Wh   = (const float*)d_in[2];
  const float* bias = (const float*)d_in[3];
  const float* fcw  = (const float*)d_in[4];
  const float* fcb  = (const float*)d_in[5];
  float* out = (float*)d_out;                 // [y 16384 | h 32768 | c 32768]

  char* ws = (char*)d_ws;
  unsigned short* Wcat = (unsigned short*)ws;                       // 3,145,728 B
  float* bcat          = (float*)(ws + 3145728);                    //     8,192 B
  unsigned* hexf       = (unsigned*)(ws + 3145728 + 8192);          //   262,144 B

  // zero hexf (both buffers; tag 0 == valid h_0) — every call (buffers persist!)
  init_kernel<<<dim3(256), dim3(256), 0, stream>>>((unsigned int*)hexf, 65536);
  // repack weights to bf16 [32][64][768] + bias [32][64]
  prep_kernel<<<dim3((KK * 2048) / 256), dim3(256), 0, stream>>>(Wx, Wh, bias, Wcat, bcat);
  // persistent recurrence: 64 WGs (2 batch groups x 32 hidden slices), 512 threads
  lstm_kernel<<<dim3(GBC * GHC), dim3(512), 0, stream>>>(
      x, Wcat, bcat, hexf, out + 16384, out + 16384 + 32768);
  // final projection
  fc_kernel<<<dim3(B_), dim3(256), 0, stream>>>(out + 16384, fcw, fcb, out);
}